// Round 3
// baseline (74.362 us; speedup 1.0000x reference)
//
#include <hip/hip_runtime.h>

// Chamfer-with-normals, B=8, C=6 (3 pos + 3 nrm), N=4096, fp32.
// d[i][j] = aa_i + (bb_j + W) + r_i.c_j,  r=(-2p_i, -W bn_i), c=(q_j, an_j)
// (cross-indexed normals; R6 MFMA formulation verified absmax=0).
//
// R10: attack the ~20us read-starvation stall. Budget calib (F~4.4us from R8):
// R9 chamfer ran ~29us vs ~8us busy model; its 4.5MB FETCH trickled at
// ~113-155 GB/s because the preceding 256MiB ws-poison fill retires with its
// data dirty in MALL (TCC WRITE_SIZE = L2->MALL, not HBM) and the HBM drain
// overlaps our kernel, starving our cold A/B reads (A/B evicted each iter).
// Levers:
//  1. XCD pinning: flat grid, bd = id&15 -> all 32 blocks of a (dir,batch)
//     group share id%8 -> one XCD (round-robin dispatch); dir0/dir1 of same
//     batch (same bytes, role-swapped) share it too. Per-XCD distinct ~384KB,
//     chip FETCH ~4.5MB -> ~3MB, sibling blocks L2-hit.
//  2. 2x MLP for the latency-bound cold reads: 8 col-splits x 512 cols,
//     32KB LDS, 4 blocks/CU (launch_bounds(256,4), 16 waves/CU). Also gives
//     4 waves/SIMD to hide MFMA->v_min3 latency in the inner loop.
// Fenceless combine kept from R9 (verified): MALL-coherent sc1 atomics,
// even-bit atomicOr arrival (0xAA poison + zero-init safe; mask now 0x5555
// for 8 splits), single f64 atomicAdd(2^24 + 0.125*gsum) whose return value
// gives last-arrival detection AND the exact final sum.
//
// Main body math unchanged: single LDS phase, [k-plane][col] interleave,
// ONE barrier, rt=8 rows/wave, one K=32 mfma_f32_16x16x32_f16 per tile:
//   A32 = [rh6|rl6|rh6|rl6| 1 1 ah al |0000], B32 = [ch6|ch6|cl6|cl6| bh bl 1 1 |0000]
// Layouts m89/m120-verified; D[row=quad*4+reg][col=lane&15].

constexpr int   NPTS  = 4096;
constexpr int   CPB   = 6;
constexpr int   BATCH = 8;
constexpr float W     = 0.001f;
constexpr int   NSPL  = 8;                // col splits of 512
constexpr int   NGRP  = 128;              // 16 bd * 8 rowgroups
constexpr double MARK = 16777216.0;       // 2^24 arrival marker

typedef _Float16 f16x8 __attribute__((ext_vector_type(8)));
typedef float    f32x4 __attribute__((ext_vector_type(4)));

#define MFMA32(A_, B_, C_) __builtin_amdgcn_mfma_f32_16x16x32_f16((A_), (B_), (C_), 0, 0, 0)
#define AST(p, v) __hip_atomic_store((p), (v), __ATOMIC_RELAXED, __HIP_MEMORY_SCOPE_AGENT)
#define ALD(p)    __hip_atomic_load((p), __ATOMIC_RELAXED, __HIP_MEMORY_SCOPE_AGENT)

__device__ inline void fsplit(float x, _Float16& h, _Float16& l) {
    h = (_Float16)x;
    l = (_Float16)(x - (float)h);
}

// Flat grid 1024: id&15 = bd (XCD = bd%8), id>>4 = {s(3b) | rg(3b)}.
// 1024 blocks = 4/CU; 256 thr = 4 waves; wave owns 8 row-tiles, 32 col-tiles.
__global__ __launch_bounds__(256, 4) void chamfer_fused_kernel(
    const float* __restrict__ A, const float* __restrict__ B,
    float* __restrict__ partial, unsigned* __restrict__ gflags,
    double* __restrict__ acc, float* __restrict__ out)
{
    const int id = blockIdx.x;
    const int bd = id & 15, sub = id >> 4;
    const int s = sub & 7, rg = sub >> 3;
    const int dir = bd >> 3, batch = bd & 7;
    const int tid = threadIdx.x, w = tid >> 6, lane = tid & 63;
    const int quad = lane >> 4, l16 = lane & 15;
    const float* rowPos = dir ? B : A;
    const float* rowNrm = dir ? A : B;
    const float* colPos = dir ? A : B;
    const float* colNrm = dir ? B : A;
    const int bb = batch * CPB * NPTS;
    const _Float16 one = (_Float16)1.f, zz = (_Float16)0.f;

    // [k-plane][col][8 f16]: plane k at k*4096 f16 (8KB); both LDS write and
    // read are lane-consecutive 16B bursts (conflict-free b128 pattern).
    __shared__ alignas(16) _Float16 lds[4 * 512 * 8];   // 32 KB
    __shared__ float sred[4];
    __shared__ int s_last;

    // ---- row raw loads FIRST: 48 loads in flight alongside col staging
    float rp[8][6];
#pragma unroll
    for (int rt = 0; rt < 8; ++rt) {
        const int row = rg * 512 + (w * 8 + rt) * 16 + l16;
        rp[rt][0] = rowPos[bb + 0*NPTS + row];
        rp[rt][1] = rowPos[bb + 1*NPTS + row];
        rp[rt][2] = rowPos[bb + 2*NPTS + row];
        rp[rt][3] = rowNrm[bb + 3*NPTS + row];
        rp[rt][4] = rowNrm[bb + 4*NPTS + row];
        rp[rt][5] = rowNrm[bb + 5*NPTS + row];
    }

    // ---- stage this block's 512 cols inline (2 cols per thread)
#pragma unroll
    for (int p = 0; p < 2; ++p) {
        const int j  = p * 256 + tid;       // col within split
        const int cj = s * 512 + j;
        const float q0 = colPos[bb + 0*NPTS + cj], q1 = colPos[bb + 1*NPTS + cj],
                    q2 = colPos[bb + 2*NPTS + cj];
        const float n0 = colNrm[bb + 3*NPTS + cj], n1 = colNrm[bb + 4*NPTS + cj],
                    n2 = colNrm[bb + 5*NPTS + cj];
        const float c6[6] = {q0, q1, q2, n0, n1, n2};
        const float bias = fmaf(q0, q0, fmaf(q1, q1, q2*q2)) + W;
        _Float16 ch[6], cl[6], bh, bl;
#pragma unroll
        for (int c = 0; c < 6; ++c) fsplit(c6[c], ch[c], cl[c]);
        fsplit(bias, bh, bl);
        f16x8 v0 = {ch[0], ch[1], ch[2], ch[3], ch[4], ch[5], ch[0], ch[1]};
        f16x8 v1 = {ch[2], ch[3], ch[4], ch[5], cl[0], cl[1], cl[2], cl[3]};
        f16x8 v2 = {cl[4], cl[5], cl[0], cl[1], cl[2], cl[3], cl[4], cl[5]};
        f16x8 v3 = {bh, bl, one, one, zz, zz, zz, zz};
        *(f16x8*)&lds[0 * 4096 + j * 8] = v0;
        *(f16x8*)&lds[1 * 4096 + j * 8] = v1;
        *(f16x8*)&lds[2 * 4096 + j * 8] = v2;
        *(f16x8*)&lds[3 * 4096 + j * 8] = v3;
    }

    // ---- A-frags from rp (quad-dependent slot expansion, verified in R6)
    f16x8 a[8];
#pragma unroll
    for (int rt = 0; rt < 8; ++rt) {
        const float p0 = rp[rt][0], p1 = rp[rt][1], p2 = rp[rt][2];
        const float r6[6] = {-2.f*p0, -2.f*p1, -2.f*p2,
                             -W*rp[rt][3], -W*rp[rt][4], -W*rp[rt][5]};
        const float aa = fmaf(p0, p0, fmaf(p1, p1, p2*p2));
        _Float16 rh[6], rl[6], ah, al;
#pragma unroll
        for (int c = 0; c < 6; ++c) fsplit(r6[c], rh[c], rl[c]);
        fsplit(aa, ah, al);
        f16x8 af;
        if (quad == 0)      af = f16x8{rh[0], rh[1], rh[2], rh[3], rh[4], rh[5], rl[0], rl[1]};
        else if (quad == 1) af = f16x8{rl[2], rl[3], rl[4], rl[5], rh[0], rh[1], rh[2], rh[3]};
        else if (quad == 2) af = f16x8{rh[4], rh[5], rl[0], rl[1], rl[2], rl[3], rl[4], rl[5]};
        else                af = f16x8{one, one, ah, al, zz, zz, zz, zz};
        a[rt] = af;
    }

    float m[8][4];
#pragma unroll
    for (int rt = 0; rt < 8; ++rt)
#pragma unroll
        for (int r_ = 0; r_ < 4; ++r_) m[rt][r_] = 3.4e38f;

    __syncthreads();                        // the main loop's only barrier

    const _Float16* lq = &lds[quad * 4096];
    const f32x4 z = {0.f, 0.f, 0.f, 0.f};
    for (int ct = 0; ct < 32; ct += 2) {
        const f16x8 b0 = *(const f16x8*)&lq[(ct * 16 + l16) * 8];
        const f16x8 b1 = *(const f16x8*)&lq[((ct + 1) * 16 + l16) * 8];
#pragma unroll
        for (int rt = 0; rt < 8; ++rt) {
            f32x4 acc0 = MFMA32(a[rt], b0, z);
            f32x4 acc1 = MFMA32(a[rt], b1, z);
#pragma unroll
            for (int r_ = 0; r_ < 4; ++r_)
                m[rt][r_] = fminf(m[rt][r_], fminf(acc0[r_], acc1[r_]));  // v_min3
        }
    }

    // finish col-min within tile: reduce over lane&15 (cols) via shfl_xor
#pragma unroll
    for (int rt = 0; rt < 8; ++rt)
#pragma unroll
        for (int r_ = 0; r_ < 4; ++r_) {
            float v = m[rt][r_];
            v = fminf(v, __shfl_xor(v, 1));
            v = fminf(v, __shfl_xor(v, 2));
            v = fminf(v, __shfl_xor(v, 4));
            v = fminf(v, __shfl_xor(v, 8));
            m[rt][r_] = v;
        }

    // partial row-mins -> MALL via agent-scope atomic stores (L2-bypassing sc1)
    if (l16 == 0) {
        float* pb = partial + ((size_t)(s * 16 + bd)) * NPTS + rg * 512;
#pragma unroll
        for (int rt = 0; rt < 8; ++rt) {
            const int rb_ = (w * 8 + rt) * 16 + quad * 4;   // D row = quad*4+reg
#pragma unroll
            for (int r_ = 0; r_ < 4; ++r_)
                AST(pb + rb_ + r_, m[rt][r_]);
        }
    }

    // ---- fenceless cross-block combine
    __syncthreads();            // barrier drains vmcnt(0): ASTs complete at MALL
    const int g = bd * 8 + rg;  // 0..127
    if (tid == 0) {
        const unsigned mybit = 1u << (2 * s);               // even bit: poison-safe
        const unsigned old = atomicOr(&gflags[g], mybit);
        s_last = (((old | mybit) & 0x5555u) == 0x5555u) ? 1 : 0;
    }
    __syncthreads();
    if (!s_last) return;        // uniform per block

    // group-last: final row-min over 8 splits (MALL-coherent loads) + 512-row sum
    float lsum = 0.f;
#pragma unroll
    for (int k = 0; k < 2; ++k) {
        const int row = rg * 512 + k * 256 + tid;
        float v = ALD(&partial[(size_t)(0 * 16 + bd) * NPTS + row]);
#pragma unroll
        for (int s2 = 1; s2 < NSPL; ++s2)
            v = fminf(v, ALD(&partial[(size_t)(s2 * 16 + bd) * NPTS + row]));
        lsum += v;
    }
    for (int off = 32; off; off >>= 1) lsum += __shfl_down(lsum, off, 64);
    if ((tid & 63) == 0) sred[tid >> 6] = lsum;
    __syncthreads();

    // level 2: ONE f64 atomicAdd carries both the value and the arrival count.
    // Exactly one block's return crosses (NGRP-1)*MARK; it holds the exact
    // final sum (old + mine is bitwise the accumulator's final IEEE value).
    if (tid == 0) {
        const double mine = (double)(sred[0] + sred[1] + sred[2] + sred[3]) * 0.125 + MARK;
        const double old  = atomicAdd(acc, mine);
        if (old > (double)(NGRP - 1) * MARK - 1000.0)
            out[0] = (float)(old + mine - (double)NGRP * MARK);
    }
}

extern "C" void kernel_launch(void* const* d_in, const int* in_sizes, int n_in,
                              void* d_out, int out_size, void* d_ws, size_t ws_size,
                              hipStream_t stream) {
    const float* A = (const float*)d_in[0];
    const float* B = (const float*)d_in[1];
    float* out     = (float*)d_out;
    float* partial = (float*)d_ws;          // 8 splits x 16 bd x 4096 f32 = 2 MB
    unsigned* gflags = (unsigned*)((char*)d_ws + (size_t)NSPL * 16 * NPTS * sizeof(float));
    double* acc      = (double*)((char*)gflags + 1024);   // 8B-aligned

    chamfer_fused_kernel<<<dim3(16 * NSPL * 8), 256, 0, stream>>>(
        A, B, partial, gflags, acc, out);
}

// Round 4
// 74.340 us; speedup vs baseline: 1.0003x; 1.0003x over previous
//
#include <hip/hip_runtime.h>

// Chamfer-with-normals, B=8, C=6 (3 pos + 3 nrm), N=4096, fp32.
// d[i][j] = aa_i + (bb_j + W) + r_i.c_j,  r=(-2p_i, -W bn_i), c=(q_j, an_j)
// (cross-indexed normals; R6 MFMA formulation verified absmax=0).
//
// R11: non-temporal A/B loads. R10 post-mortem: XCD pinning + 2x MLP both
// NULL vs the ~20us stall -> stall is not MLP/locality. MALL is die-level so
// HBM-side cold demand was always just the distinct 1.5MB of A/B; 1.5MB/20us
// = 75 GB/s = ~1% of read BW. Mechanism: the 256MiB poison fill leaves MALL
// (256MiB) and all L2s ENTIRELY dirty; every cold A/B read must allocate ->
// evict a dirty victim -> writeback-before-fetch, throttled by the eviction
// engine's writeback slots (cache-side queue => kernel-side MLP can't help).
// Fix attempt: __builtin_nontemporal_load (global_load ... nt = no-allocate,
// last-use) on ALL A/B reads: no allocation => no dirty-victim stall; cold
// reads become plain HBM-latency streaming that 4 blocks/CU MLP covers
// (~24K lines / ~2K outstanding x ~400ns ~ 5us). Falsifier: <2us move =>
// fixed post-fill drain window, harness floor reached -> ROOFLINE.
//
// Kept from R10 (all verified absmax=0): flat-grid XCD pinning (bd=id&15),
// 8 col-splits x 512, 32KB LDS, 4 blocks/CU; fenceless combine: MALL-coherent
// sc1 atomics for partial, even-bit atomicOr arrival (0xAA/zero-init safe,
// mask 0x5555), single f64 atomicAdd(2^24 + 0.125*gsum) whose return gives
// last-arrival detection AND the exact final sum.
//
// Main body math unchanged: single LDS phase, [k-plane][col] interleave,
// ONE barrier, rt=8 rows/wave, one K=32 mfma_f32_16x16x32_f16 per tile:
//   A32 = [rh6|rl6|rh6|rl6| 1 1 ah al |0000], B32 = [ch6|ch6|cl6|cl6| bh bl 1 1 |0000]
// Layouts m89/m120-verified; D[row=quad*4+reg][col=lane&15].

constexpr int   NPTS  = 4096;
constexpr int   CPB   = 6;
constexpr int   BATCH = 8;
constexpr float W     = 0.001f;
constexpr int   NSPL  = 8;                // col splits of 512
constexpr int   NGRP  = 128;              // 16 bd * 8 rowgroups
constexpr double MARK = 16777216.0;       // 2^24 arrival marker

typedef _Float16 f16x8 __attribute__((ext_vector_type(8)));
typedef float    f32x4 __attribute__((ext_vector_type(4)));

#define MFMA32(A_, B_, C_) __builtin_amdgcn_mfma_f32_16x16x32_f16((A_), (B_), (C_), 0, 0, 0)
#define AST(p, v) __hip_atomic_store((p), (v), __ATOMIC_RELAXED, __HIP_MEMORY_SCOPE_AGENT)
#define ALD(p)    __hip_atomic_load((p), __ATOMIC_RELAXED, __HIP_MEMORY_SCOPE_AGENT)

__device__ inline float ntld(const float* __restrict__ p) {
    return __builtin_nontemporal_load(p);
}

__device__ inline void fsplit(float x, _Float16& h, _Float16& l) {
    h = (_Float16)x;
    l = (_Float16)(x - (float)h);
}

// Flat grid 1024: id&15 = bd (XCD = bd%8), id>>4 = {s(3b) | rg(3b)}.
// 1024 blocks = 4/CU; 256 thr = 4 waves; wave owns 8 row-tiles, 32 col-tiles.
__global__ __launch_bounds__(256, 4) void chamfer_fused_kernel(
    const float* __restrict__ A, const float* __restrict__ B,
    float* __restrict__ partial, unsigned* __restrict__ gflags,
    double* __restrict__ acc, float* __restrict__ out)
{
    const int id = blockIdx.x;
    const int bd = id & 15, sub = id >> 4;
    const int s = sub & 7, rg = sub >> 3;
    const int dir = bd >> 3, batch = bd & 7;
    const int tid = threadIdx.x, w = tid >> 6, lane = tid & 63;
    const int quad = lane >> 4, l16 = lane & 15;
    const float* rowPos = dir ? B : A;
    const float* rowNrm = dir ? A : B;
    const float* colPos = dir ? A : B;
    const float* colNrm = dir ? B : A;
    const int bb = batch * CPB * NPTS;
    const _Float16 one = (_Float16)1.f, zz = (_Float16)0.f;

    // [k-plane][col][8 f16]: plane k at k*4096 f16 (8KB); both LDS write and
    // read are lane-consecutive 16B bursts (conflict-free b128 pattern).
    __shared__ alignas(16) _Float16 lds[4 * 512 * 8];   // 32 KB
    __shared__ float sred[4];
    __shared__ int s_last;

    // ---- row raw loads FIRST (nt): 48 loads in flight alongside col staging
    float rp[8][6];
#pragma unroll
    for (int rt = 0; rt < 8; ++rt) {
        const int row = rg * 512 + (w * 8 + rt) * 16 + l16;
        rp[rt][0] = ntld(&rowPos[bb + 0*NPTS + row]);
        rp[rt][1] = ntld(&rowPos[bb + 1*NPTS + row]);
        rp[rt][2] = ntld(&rowPos[bb + 2*NPTS + row]);
        rp[rt][3] = ntld(&rowNrm[bb + 3*NPTS + row]);
        rp[rt][4] = ntld(&rowNrm[bb + 4*NPTS + row]);
        rp[rt][5] = ntld(&rowNrm[bb + 5*NPTS + row]);
    }

    // ---- stage this block's 512 cols inline (2 cols per thread, nt loads)
#pragma unroll
    for (int p = 0; p < 2; ++p) {
        const int j  = p * 256 + tid;       // col within split
        const int cj = s * 512 + j;
        const float q0 = ntld(&colPos[bb + 0*NPTS + cj]),
                    q1 = ntld(&colPos[bb + 1*NPTS + cj]),
                    q2 = ntld(&colPos[bb + 2*NPTS + cj]);
        const float n0 = ntld(&colNrm[bb + 3*NPTS + cj]),
                    n1 = ntld(&colNrm[bb + 4*NPTS + cj]),
                    n2 = ntld(&colNrm[bb + 5*NPTS + cj]);
        const float c6[6] = {q0, q1, q2, n0, n1, n2};
        const float bias = fmaf(q0, q0, fmaf(q1, q1, q2*q2)) + W;
        _Float16 ch[6], cl[6], bh, bl;
#pragma unroll
        for (int c = 0; c < 6; ++c) fsplit(c6[c], ch[c], cl[c]);
        fsplit(bias, bh, bl);
        f16x8 v0 = {ch[0], ch[1], ch[2], ch[3], ch[4], ch[5], ch[0], ch[1]};
        f16x8 v1 = {ch[2], ch[3], ch[4], ch[5], cl[0], cl[1], cl[2], cl[3]};
        f16x8 v2 = {cl[4], cl[5], cl[0], cl[1], cl[2], cl[3], cl[4], cl[5]};
        f16x8 v3 = {bh, bl, one, one, zz, zz, zz, zz};
        *(f16x8*)&lds[0 * 4096 + j * 8] = v0;
        *(f16x8*)&lds[1 * 4096 + j * 8] = v1;
        *(f16x8*)&lds[2 * 4096 + j * 8] = v2;
        *(f16x8*)&lds[3 * 4096 + j * 8] = v3;
    }

    // ---- A-frags from rp (quad-dependent slot expansion, verified in R6)
    f16x8 a[8];
#pragma unroll
    for (int rt = 0; rt < 8; ++rt) {
        const float p0 = rp[rt][0], p1 = rp[rt][1], p2 = rp[rt][2];
        const float r6[6] = {-2.f*p0, -2.f*p1, -2.f*p2,
                             -W*rp[rt][3], -W*rp[rt][4], -W*rp[rt][5]};
        const float aa = fmaf(p0, p0, fmaf(p1, p1, p2*p2));
        _Float16 rh[6], rl[6], ah, al;
#pragma unroll
        for (int c = 0; c < 6; ++c) fsplit(r6[c], rh[c], rl[c]);
        fsplit(aa, ah, al);
        f16x8 af;
        if (quad == 0)      af = f16x8{rh[0], rh[1], rh[2], rh[3], rh[4], rh[5], rl[0], rl[1]};
        else if (quad == 1) af = f16x8{rl[2], rl[3], rl[4], rl[5], rh[0], rh[1], rh[2], rh[3]};
        else if (quad == 2) af = f16x8{rh[4], rh[5], rl[0], rl[1], rl[2], rl[3], rl[4], rl[5]};
        else                af = f16x8{one, one, ah, al, zz, zz, zz, zz};
        a[rt] = af;
    }

    float m[8][4];
#pragma unroll
    for (int rt = 0; rt < 8; ++rt)
#pragma unroll
        for (int r_ = 0; r_ < 4; ++r_) m[rt][r_] = 3.4e38f;

    __syncthreads();                        // the main loop's only barrier

    const _Float16* lq = &lds[quad * 4096];
    const f32x4 z = {0.f, 0.f, 0.f, 0.f};
    for (int ct = 0; ct < 32; ct += 2) {
        const f16x8 b0 = *(const f16x8*)&lq[(ct * 16 + l16) * 8];
        const f16x8 b1 = *(const f16x8*)&lq[((ct + 1) * 16 + l16) * 8];
#pragma unroll
        for (int rt = 0; rt < 8; ++rt) {
            f32x4 acc0 = MFMA32(a[rt], b0, z);
            f32x4 acc1 = MFMA32(a[rt], b1, z);
#pragma unroll
            for (int r_ = 0; r_ < 4; ++r_)
                m[rt][r_] = fminf(m[rt][r_], fminf(acc0[r_], acc1[r_]));  // v_min3
        }
    }

    // finish col-min within tile: reduce over lane&15 (cols) via shfl_xor
#pragma unroll
    for (int rt = 0; rt < 8; ++rt)
#pragma unroll
        for (int r_ = 0; r_ < 4; ++r_) {
            float v = m[rt][r_];
            v = fminf(v, __shfl_xor(v, 1));
            v = fminf(v, __shfl_xor(v, 2));
            v = fminf(v, __shfl_xor(v, 4));
            v = fminf(v, __shfl_xor(v, 8));
            m[rt][r_] = v;
        }

    // partial row-mins -> MALL via agent-scope atomic stores (L2-bypassing sc1)
    if (l16 == 0) {
        float* pb = partial + ((size_t)(s * 16 + bd)) * NPTS + rg * 512;
#pragma unroll
        for (int rt = 0; rt < 8; ++rt) {
            const int rb_ = (w * 8 + rt) * 16 + quad * 4;   // D row = quad*4+reg
#pragma unroll
            for (int r_ = 0; r_ < 4; ++r_)
                AST(pb + rb_ + r_, m[rt][r_]);
        }
    }

    // ---- fenceless cross-block combine
    __syncthreads();            // barrier drains vmcnt(0): ASTs complete at MALL
    const int g = bd * 8 + rg;  // 0..127
    if (tid == 0) {
        const unsigned mybit = 1u << (2 * s);               // even bit: poison-safe
        const unsigned old = atomicOr(&gflags[g], mybit);
        s_last = (((old | mybit) & 0x5555u) == 0x5555u) ? 1 : 0;
    }
    __syncthreads();
    if (!s_last) return;        // uniform per block

    // group-last: final row-min over 8 splits (MALL-coherent loads) + 512-row sum
    float lsum = 0.f;
#pragma unroll
    for (int k = 0; k < 2; ++k) {
        const int row = rg * 512 + k * 256 + tid;
        float v = ALD(&partial[(size_t)(0 * 16 + bd) * NPTS + row]);
#pragma unroll
        for (int s2 = 1; s2 < NSPL; ++s2)
            v = fminf(v, ALD(&partial[(size_t)(s2 * 16 + bd) * NPTS + row]));
        lsum += v;
    }
    for (int off = 32; off; off >>= 1) lsum += __shfl_down(lsum, off, 64);
    if ((tid & 63) == 0) sred[tid >> 6] = lsum;
    __syncthreads();

    // level 2: ONE f64 atomicAdd carries both the value and the arrival count.
    // Exactly one block's return crosses (NGRP-1)*MARK; it holds the exact
    // final sum (old + mine is bitwise the accumulator's final IEEE value).
    if (tid == 0) {
        const double mine = (double)(sred[0] + sred[1] + sred[2] + sred[3]) * 0.125 + MARK;
        const double old  = atomicAdd(acc, mine);
        if (old > (double)(NGRP - 1) * MARK - 1000.0)
            out[0] = (float)(old + mine - (double)NGRP * MARK);
    }
}

extern "C" void kernel_launch(void* const* d_in, const int* in_sizes, int n_in,
                              void* d_out, int out_size, void* d_ws, size_t ws_size,
                              hipStream_t stream) {
    const float* A = (const float*)d_in[0];
    const float* B = (const float*)d_in[1];
    float* out     = (float*)d_out;
    float* partial = (float*)d_ws;          // 8 splits x 16 bd x 4096 f32 = 2 MB
    unsigned* gflags = (unsigned*)((char*)d_ws + (size_t)NSPL * 16 * NPTS * sizeof(float));
    double* acc      = (double*)((char*)gflags + 1024);   // 8B-aligned

    chamfer_fused_kernel<<<dim3(16 * NSPL * 8), 256, 0, stream>>>(
        A, B, partial, gflags, acc, out);
}